// Round 2
// baseline (1819.687 us; speedup 1.0000x reference)
//
#include <hip/hip_runtime.h>

#define NFEAT 64
#define NCLS  100
#define ACC   (NCLS * NFEAT)          // 6400
#define FBLK  512                     // 2 blocks/CU on 256 CUs (103 KB LDS/CU)
#define FTHR  1024                    // 16 waves/block -> 32 waves/CU

// ws layout in 32-bit words
#define OFF_GS    0                   // 6400 f32 reduced sums
#define OFF_GSS   6400                // 6400 f32 reduced sum-squares
#define OFF_GCNT  12800               // 100 u32 class counts
#define OFF_PART  12928               // FBLK * 2*ACC f32 per-block partials (~26 MB)

__global__ void zero_u32_kernel(unsigned* __restrict__ p, int n) {
    int i = blockIdx.x * blockDim.x + threadIdx.x;
    if (i < n) p[i] = 0u;
}

// One pass over x (perfectly coalesced streaming) + t. Per-block LDS
// accumulators; ds_add_f32 addresses are c*64+lane -> bank = lane%32,
// 2-way aliasing only (free). Flush to private global partials (no
// global-atomic contention), counts via 100 global atomics per block.
__global__ __launch_bounds__(FTHR, 8)
void fused_accum(const float* __restrict__ x, const int* __restrict__ t,
                 float* __restrict__ partials,
                 float* __restrict__ gs, float* __restrict__ gss,
                 unsigned* __restrict__ gcnt, int n, int atomic_flush) {
    __shared__ float ls[ACC];
    __shared__ float lss[ACC];
    __shared__ unsigned lcnt[NCLS];
    const int tid = threadIdx.x;
    for (int i = tid; i < ACC; i += FTHR) { ls[i] = 0.f; lss[i] = 0.f; }
    if (tid < NCLS) lcnt[tid] = 0u;
    __syncthreads();

    const int lane = tid & 63;
    const int wave = tid >> 6;
    const long long step = (long long)FBLK * (FTHR / 64) * 8;   // rows per grid sweep
    long long row0 = ((long long)blockIdx.x * (FTHR / 64) + wave) * 8;

    for (; row0 + 8 <= n; row0 += step) {
        const int*   tp = t + row0;
        const float* xp = x + row0 * NFEAT + lane;
        int c[8]; float v[8];
#pragma unroll
        for (int u = 0; u < 8; u++) c[u] = __builtin_amdgcn_readfirstlane(tp[u]);
#pragma unroll
        for (int u = 0; u < 8; u++) v[u] = xp[u * NFEAT];   // wave reads 2 KB contiguous

        // per-row count: lanes 0..7 each add 1 for one row (static reg indexing)
        int myc = c[0];
        if (lane == 1) myc = c[1];
        if (lane == 2) myc = c[2];
        if (lane == 3) myc = c[3];
        if (lane == 4) myc = c[4];
        if (lane == 5) myc = c[5];
        if (lane == 6) myc = c[6];
        if (lane == 7) myc = c[7];
        if (lane < 8) atomicAdd(&lcnt[myc], 1u);

#pragma unroll
        for (int u = 0; u < 8; u++) {
            const int base = c[u] * NFEAT + lane;
            unsafeAtomicAdd(&ls[base],  v[u]);
            unsafeAtomicAdd(&lss[base], v[u] * v[u]);
        }
    }
    // tail (n % 8 != 0 case; at most one wave enters)
    for (; row0 < n; row0++) {
        const int c0 = __builtin_amdgcn_readfirstlane(t[row0]);
        const float vv = x[row0 * NFEAT + lane];
        unsafeAtomicAdd(&ls[c0 * NFEAT + lane],  vv);
        unsafeAtomicAdd(&lss[c0 * NFEAT + lane], vv * vv);
        if (lane == 0) atomicAdd(&lcnt[c0], 1u);
    }
    __syncthreads();

    if (atomic_flush) {
        for (int i = tid; i < ACC; i += FTHR) {
            unsafeAtomicAdd(&gs[i],  ls[i]);
            unsafeAtomicAdd(&gss[i], lss[i]);
        }
    } else {
        float* pb = partials + (size_t)blockIdx.x * (2 * ACC);
        for (int i = tid; i < ACC; i += FTHR) {
            pb[i]       = ls[i];
            pb[ACC + i] = lss[i];
        }
    }
    if (tid < NCLS) {
        const unsigned vv = lcnt[tid];
        if (vv) atomicAdd(&gcnt[tid], vv);
    }
}

// Fold FBLK per-block partials: thread j sums column j (coalesced across
// threads for each b). 26 MB total -> ~5 us.
__global__ __launch_bounds__(256)
void reduce_partials(const float* __restrict__ part, float* __restrict__ gsgss) {
    const int j = blockIdx.x * 256 + threadIdx.x;
    if (j >= 2 * ACC) return;
    const float* p = part + j;
    double a0 = 0.0, a1 = 0.0, a2 = 0.0, a3 = 0.0;
    for (int b = 0; b < FBLK; b += 4) {
        a0 += (double)p[(size_t)(b + 0) * (2 * ACC)];
        a1 += (double)p[(size_t)(b + 1) * (2 * ACC)];
        a2 += (double)p[(size_t)(b + 2) * (2 * ACC)];
        a3 += (double)p[(size_t)(b + 3) * (2 * ACC)];
    }
    gsgss[j] = (float)((a0 + a1) + (a2 + a3));
}

__global__ void finalize_kernel(const float* __restrict__ gs,
                                const float* __restrict__ gss,
                                const unsigned int* __restrict__ gcnt,
                                float* __restrict__ out) {
    __shared__ double red[256];
    double acc = 0.0;
    for (int i = threadIdx.x; i < ACC; i += 256) {
        const int c = i >> 6;
        const double n  = (double)gcnt[c];
        const double s  = (double)gs[i];
        const double ss = (double)gss[i];
        acc += (ss - s * s / n) / (n - 1.0);
    }
    red[threadIdx.x] = acc;
    __syncthreads();
    for (int off = 128; off > 0; off >>= 1) {
        if (threadIdx.x < off) red[threadIdx.x] += red[threadIdx.x + off];
        __syncthreads();
    }
    if (threadIdx.x == 0) out[0] = (float)(red[0] / (double)NCLS);
}

extern "C" void kernel_launch(void* const* d_in, const int* in_sizes, int n_in,
                              void* d_out, int out_size, void* d_ws, size_t ws_size,
                              hipStream_t stream) {
    const float* x = (const float*)d_in[0];
    const int*   t = (const int*)d_in[1];
    const int n = in_sizes[1];               // 2,000,000

    float*    wsf  = (float*)d_ws;
    unsigned* wsu  = (unsigned*)d_ws;
    float*    gs   = wsf + OFF_GS;
    float*    gss  = wsf + OFF_GSS;
    unsigned* gcnt = wsu + OFF_GCNT;
    float*    part = wsf + OFF_PART;

    const size_t needed = ((size_t)OFF_PART + (size_t)FBLK * 2 * ACC) * 4;

    if (ws_size >= needed) {
        // main path: only gcnt needs zeroing (gs/gss fully written by reduce,
        // partials fully written by fused_accum)
        zero_u32_kernel<<<1, 128, 0, stream>>>(gcnt, NCLS);
        fused_accum<<<FBLK, FTHR, 0, stream>>>(x, t, part, gs, gss, gcnt, n, 0);
        reduce_partials<<<(2 * ACC + 255) / 256, 256, 0, stream>>>(part, wsf);
        finalize_kernel<<<1, 256, 0, stream>>>(gs, gss, gcnt, (float*)d_out);
    } else {
        // small-ws fallback: atomic flush directly into zeroed gs/gss
        zero_u32_kernel<<<(12900 + 255) / 256, 256, 0, stream>>>(wsu, 2 * ACC + NCLS);
        fused_accum<<<FBLK, FTHR, 0, stream>>>(x, t, nullptr, gs, gss, gcnt, n, 1);
        finalize_kernel<<<1, 256, 0, stream>>>(gs, gss, gcnt, (float*)d_out);
    }
}

// Round 3
// 1818.128 us; speedup vs baseline: 1.0009x; 1.0009x over previous
//
#include <hip/hip_runtime.h>

#define NFEAT 64
#define NCLS  100
#define ACC   (NCLS * NFEAT)   // 6400
#define FBLK  512              // 2 blocks/CU (103 KB LDS/CU), 32 waves/CU
#define FTHR  1024
#define NB    512              // hist blocks

// ws layout (32-bit words) — total 12900 words = 51.6 KB
#define OFF_GS    0            // 6400 f32
#define OFF_GSS   6400         // 6400 f32
#define OFF_GCNT  12800        // 100 u32
#define ZWORDS    (2 * ACC + NCLS)

__global__ void zero_u32_kernel(unsigned* __restrict__ p, int n) {
    int i = blockIdx.x * blockDim.x + threadIdx.x;
    if (i < n) p[i] = 0u;
}

// Counts only (proven structure from the 718us session). 8 MB re-read of t.
__global__ __launch_bounds__(256, 4)
void hist_kernel(const int* __restrict__ t, unsigned* __restrict__ gcnt,
                 int n, int chunk) {
    __shared__ unsigned h[NCLS];
    for (int i = threadIdx.x; i < NCLS; i += 256) h[i] = 0u;
    __syncthreads();
    const int b = blockIdx.x, s = b * chunk, e = min(n, s + chunk);
    for (int i = s + threadIdx.x; i < e; i += 256) atomicAdd(&h[t[i]], 1u);
    __syncthreads();
    for (int c = threadIdx.x; c < NCLS; c += 256) {
        const unsigned v = h[c];
        if (v) atomicAdd(&gcnt[c], v);
    }
}

// Streaming pass over x: wave reads 8 contiguous rows (2 KB), lane = feature.
// NO arrays, NO readfirstlane in the hot loop — classes stay as wave-uniform
// VGPRs feeding ds_add_f32 addresses directly (c*64+lane -> 2-way bank alias,
// free). LDS accumulators flushed via global f32 atomics (12800 words).
__global__ __launch_bounds__(FTHR, 8)
void fused_accum(const float* __restrict__ x, const int* __restrict__ t,
                 float* __restrict__ gs, float* __restrict__ gss, int n) {
    __shared__ float ls[ACC];
    __shared__ float lss[ACC];
    const int tid = threadIdx.x;
    for (int i = tid; i < ACC; i += FTHR) { ls[i] = 0.f; lss[i] = 0.f; }
    __syncthreads();

    const int lane = tid & 63;
    const int wave = tid >> 6;
    const long long step = (long long)FBLK * (FTHR / 64) * 8;   // 65536 rows/sweep
    long long row0 = ((long long)blockIdx.x * (FTHR / 64) + wave) * 8;

    for (; row0 + 8 <= n; row0 += step) {
        const int4 ca = *reinterpret_cast<const int4*>(t + row0);      // rows 0..3
        const int4 cb = *reinterpret_cast<const int4*>(t + row0 + 4);  // rows 4..7
        const float* xp = x + row0 * NFEAT + lane;
        const float v0 = xp[0 * NFEAT];
        const float v1 = xp[1 * NFEAT];
        const float v2 = xp[2 * NFEAT];
        const float v3 = xp[3 * NFEAT];
        const float v4 = xp[4 * NFEAT];
        const float v5 = xp[5 * NFEAT];
        const float v6 = xp[6 * NFEAT];
        const float v7 = xp[7 * NFEAT];

        unsafeAtomicAdd(&ls [ca.x * NFEAT + lane], v0);
        unsafeAtomicAdd(&lss[ca.x * NFEAT + lane], v0 * v0);
        unsafeAtomicAdd(&ls [ca.y * NFEAT + lane], v1);
        unsafeAtomicAdd(&lss[ca.y * NFEAT + lane], v1 * v1);
        unsafeAtomicAdd(&ls [ca.z * NFEAT + lane], v2);
        unsafeAtomicAdd(&lss[ca.z * NFEAT + lane], v2 * v2);
        unsafeAtomicAdd(&ls [ca.w * NFEAT + lane], v3);
        unsafeAtomicAdd(&lss[ca.w * NFEAT + lane], v3 * v3);
        unsafeAtomicAdd(&ls [cb.x * NFEAT + lane], v4);
        unsafeAtomicAdd(&lss[cb.x * NFEAT + lane], v4 * v4);
        unsafeAtomicAdd(&ls [cb.y * NFEAT + lane], v5);
        unsafeAtomicAdd(&lss[cb.y * NFEAT + lane], v5 * v5);
        unsafeAtomicAdd(&ls [cb.z * NFEAT + lane], v6);
        unsafeAtomicAdd(&lss[cb.z * NFEAT + lane], v6 * v6);
        unsafeAtomicAdd(&ls [cb.w * NFEAT + lane], v7);
        unsafeAtomicAdd(&lss[cb.w * NFEAT + lane], v7 * v7);
    }
    // tail (n % 8 != 0) — named scalars only
    for (; row0 < n; row0++) {
        const int c0 = t[row0];
        const float vv = x[row0 * NFEAT + lane];
        unsafeAtomicAdd(&ls [c0 * NFEAT + lane], vv);
        unsafeAtomicAdd(&lss[c0 * NFEAT + lane], vv * vv);
    }
    __syncthreads();

    for (int i = tid; i < ACC; i += FTHR) {
        unsafeAtomicAdd(&gs[i],  ls[i]);
        unsafeAtomicAdd(&gss[i], lss[i]);
    }
}

__global__ void finalize_kernel(const float* __restrict__ gs,
                                const float* __restrict__ gss,
                                const unsigned int* __restrict__ gcnt,
                                float* __restrict__ out) {
    __shared__ double red[256];
    double acc = 0.0;
    for (int i = threadIdx.x; i < ACC; i += 256) {
        const int c = i >> 6;
        const double n  = (double)gcnt[c];
        const double s  = (double)gs[i];
        const double ss = (double)gss[i];
        acc += (ss - s * s / n) / (n - 1.0);
    }
    red[threadIdx.x] = acc;
    __syncthreads();
    for (int off = 128; off > 0; off >>= 1) {
        if (threadIdx.x < off) red[threadIdx.x] += red[threadIdx.x + off];
        __syncthreads();
    }
    if (threadIdx.x == 0) out[0] = (float)(red[0] / (double)NCLS);
}

extern "C" void kernel_launch(void* const* d_in, const int* in_sizes, int n_in,
                              void* d_out, int out_size, void* d_ws, size_t ws_size,
                              hipStream_t stream) {
    const float* x = (const float*)d_in[0];
    const int*   t = (const int*)d_in[1];
    const int n = in_sizes[1];               // 2,000,000

    float*    wsf  = (float*)d_ws;
    unsigned* wsu  = (unsigned*)d_ws;
    float*    gs   = wsf + OFF_GS;
    float*    gss  = wsf + OFF_GSS;
    unsigned* gcnt = wsu + OFF_GCNT;

    zero_u32_kernel<<<(ZWORDS + 255) / 256, 256, 0, stream>>>(wsu, ZWORDS);
    const int chunk = (n + NB - 1) / NB;
    hist_kernel<<<NB, 256, 0, stream>>>(t, gcnt, n, chunk);
    fused_accum<<<FBLK, FTHR, 0, stream>>>(x, t, gs, gss, n);
    finalize_kernel<<<1, 256, 0, stream>>>(gs, gss, gcnt, (float*)d_out);
}

// Round 4
// 749.743 us; speedup vs baseline: 2.4271x; 2.4250x over previous
//
#include <hip/hip_runtime.h>

#define NFEAT 64
#define NCLS  100
#define ACC   (NCLS * NFEAT)   // 6400
#define FBLK  512              // grid: 2 blocks/CU
#define FTHR  1024             // 16 waves/block
#define RTILE 4096             // rows per tile (idx fits u16)

// ws layout (32-bit words)
#define OFF_GS    0            // 6400 f32
#define OFF_GSS   6400         // 6400 f32
#define OFF_GCNT  12800        // 100 u32
#define OFF_PART  12928        // FBLK * 2*ACC f32 (~26 MB)
#define ZWORDS    (2 * ACC + NCLS)

__global__ void zero_u32_kernel(unsigned* __restrict__ p, int n) {
    int i = blockIdx.x * blockDim.x + threadIdx.x;
    if (i < n) p[i] = 0u;
}

// Block-local counting sort + register accumulation over class runs.
// LDS atomics per row: 2 (hist + scatter) instead of 128 -> removes the
// ds_add_f32 serialization wall identified in rounds 2/3.
__global__ __launch_bounds__(FTHR, 8)
void fused_accum(const float* __restrict__ x, const int* __restrict__ t,
                 float* __restrict__ partials, unsigned* __restrict__ gcnt,
                 float* __restrict__ gs, float* __restrict__ gss,
                 int n, int ntiles, int atomic_flush) {
    __shared__ float    ls[ACC];
    __shared__ float    lss[ACC];
    __shared__ unsigned cnt[NCLS];
    __shared__ unsigned base[NCLS];
    __shared__ unsigned cur[NCLS];
    __shared__ unsigned posbuf[RTILE];   // (class<<16) | tile-local row idx

    const int tid  = threadIdx.x;
    const int lane = tid & 63;
    const int w    = tid >> 6;

    for (int i = tid; i < ACC; i += FTHR) { ls[i] = 0.f; lss[i] = 0.f; }

    for (int tile = blockIdx.x; tile < ntiles; tile += gridDim.x) {
        const int r0 = tile * RTILE;
        const int e  = min(RTILE, n - r0);

        if (tid < NCLS) cnt[tid] = 0u;
        __syncthreads();

        // 1. class histogram for this tile (1 LDS atomic per row)
        for (int i = tid; i < e; i += FTHR) atomicAdd(&cnt[t[r0 + i]], 1u);
        __syncthreads();

        // 2. exclusive scan of 100 counts — single wave, shuffle scan
        if (tid < 64) {
            const int c0 = 2 * tid, c1 = 2 * tid + 1;
            const unsigned a = (c0 < NCLS) ? cnt[c0] : 0u;
            const unsigned b = (c1 < NCLS) ? cnt[c1] : 0u;
            const unsigned sv = a + b;
            unsigned incl = sv;
#pragma unroll
            for (int d = 1; d < 64; d <<= 1) {
                const unsigned o = __shfl_up(incl, d, 64);
                if (tid >= d) incl += o;
            }
            const unsigned excl = incl - sv;
            if (c0 < NCLS) base[c0] = excl;
            if (c1 < NCLS) base[c1] = excl + a;
        }
        __syncthreads();
        if (tid < NCLS) {
            cur[tid] = base[tid];
            const unsigned vv = cnt[tid];
            if (vv) atomicAdd(&gcnt[tid], vv);   // global counts, once per tile
        }
        __syncthreads();

        // 3. scatter packed (class, idx) into sorted position order
        for (int i = tid; i < e; i += FTHR) {
            const int c = t[r0 + i];
            const unsigned p = atomicAdd(&cur[c], 1u);
            posbuf[p] = ((unsigned)c << 16) | (unsigned)i;
        }
        __syncthreads();

        // 4. register accumulation over class runs; LDS atomic only at run ends
        const int q  = (e + 15) >> 4;        // positions per wave (16 waves)
        const int p0 = w * q;
        const int p1 = min(e, p0 + q);
        if (p0 < p1) {
            unsigned pk = posbuf[p0];
            int cprev = (int)(pk >> 16);
            float s = 0.f, ss = 0.f;
            for (int p = p0; p < p1; ++p) {
                pk = posbuf[p];                               // broadcast read
                const int c = (int)(pk >> 16);
                const float v = x[(long long)(r0 + (int)(pk & 0xffffu)) * NFEAT + lane];
                if (c != cprev) {                              // wave-uniform branch
                    unsafeAtomicAdd(&ls [cprev * NFEAT + lane], s);
                    unsafeAtomicAdd(&lss[cprev * NFEAT + lane], ss);
                    cprev = c; s = 0.f; ss = 0.f;
                }
                s += v; ss += v * v;
            }
            unsafeAtomicAdd(&ls [cprev * NFEAT + lane], s);
            unsafeAtomicAdd(&lss[cprev * NFEAT + lane], ss);
        }
        __syncthreads();   // posbuf/cnt reuse in next tile
    }

    // flush block accumulators
    if (atomic_flush) {
        for (int i = tid; i < ACC; i += FTHR) {
            unsafeAtomicAdd(&gs[i],  ls[i]);
            unsafeAtomicAdd(&gss[i], lss[i]);
        }
    } else {
        float* pb = partials + (size_t)blockIdx.x * (2 * ACC);
        for (int i = tid; i < ACC; i += FTHR) {
            pb[i]       = ls[i];
            pb[ACC + i] = lss[i];
        }
    }
}

__global__ __launch_bounds__(256)
void reduce_partials(const float* __restrict__ part, float* __restrict__ gsgss) {
    const int j = blockIdx.x * 256 + threadIdx.x;
    if (j >= 2 * ACC) return;
    const float* p = part + j;
    double a0 = 0.0, a1 = 0.0, a2 = 0.0, a3 = 0.0;
    for (int b = 0; b < FBLK; b += 4) {
        a0 += (double)p[(size_t)(b + 0) * (2 * ACC)];
        a1 += (double)p[(size_t)(b + 1) * (2 * ACC)];
        a2 += (double)p[(size_t)(b + 2) * (2 * ACC)];
        a3 += (double)p[(size_t)(b + 3) * (2 * ACC)];
    }
    gsgss[j] = (float)((a0 + a1) + (a2 + a3));
}

__global__ void finalize_kernel(const float* __restrict__ gs,
                                const float* __restrict__ gss,
                                const unsigned int* __restrict__ gcnt,
                                float* __restrict__ out) {
    __shared__ double red[256];
    double acc = 0.0;
    for (int i = threadIdx.x; i < ACC; i += 256) {
        const int c = i >> 6;
        const double n  = (double)gcnt[c];
        const double s  = (double)gs[i];
        const double ss = (double)gss[i];
        acc += (ss - s * s / n) / (n - 1.0);
    }
    red[threadIdx.x] = acc;
    __syncthreads();
    for (int off = 128; off > 0; off >>= 1) {
        if (threadIdx.x < off) red[threadIdx.x] += red[threadIdx.x + off];
        __syncthreads();
    }
    if (threadIdx.x == 0) out[0] = (float)(red[0] / (double)NCLS);
}

extern "C" void kernel_launch(void* const* d_in, const int* in_sizes, int n_in,
                              void* d_out, int out_size, void* d_ws, size_t ws_size,
                              hipStream_t stream) {
    const float* x = (const float*)d_in[0];
    const int*   t = (const int*)d_in[1];
    const int n = in_sizes[1];               // 2,000,000

    float*    wsf  = (float*)d_ws;
    unsigned* wsu  = (unsigned*)d_ws;
    float*    gs   = wsf + OFF_GS;
    float*    gss  = wsf + OFF_GSS;
    unsigned* gcnt = wsu + OFF_GCNT;
    float*    part = wsf + OFF_PART;

    const int ntiles = (n + RTILE - 1) / RTILE;
    const size_t needed = ((size_t)OFF_PART + (size_t)FBLK * 2 * ACC) * 4;

    if (ws_size >= needed) {
        zero_u32_kernel<<<1, 128, 0, stream>>>(gcnt, NCLS);
        fused_accum<<<FBLK, FTHR, 0, stream>>>(x, t, part, gcnt, gs, gss, n, ntiles, 0);
        reduce_partials<<<(2 * ACC + 255) / 256, 256, 0, stream>>>(part, wsf);
        finalize_kernel<<<1, 256, 0, stream>>>(gs, gss, gcnt, (float*)d_out);
    } else {
        zero_u32_kernel<<<(ZWORDS + 255) / 256, 256, 0, stream>>>(wsu, ZWORDS);
        fused_accum<<<FBLK, FTHR, 0, stream>>>(x, t, nullptr, gcnt, gs, gss, n, ntiles, 1);
        finalize_kernel<<<1, 256, 0, stream>>>(gs, gss, gcnt, (float*)d_out);
    }
}